// Round 8
// baseline (130.736 us; speedup 1.0000x reference)
//
#include <hip/hip_runtime.h>
#include <hip/hip_bf16.h>

// Problem constants
#define V_WORDS 32000
#define NSPEC 4
#define DIM 128
#define LATENT 10000
#define LT_STRIDE 10112      // padded fp8 V^T row length (bytes)
#define TOTAL_NGRAMS 704000
#define NTOK 8192
#define MAXU 8192
#define KSPLIT 8
#define KCH 1280             // k-range per split (last: 10000-7*1280=1040)
#define BK 64
#define BQBLK 64             // q rows per block (1 wave x 64)
#define SEG_BLOCKS 2048      // MAXU/4
#define BOUND_BLOCKS 2750    // 704000/256
#define CONV_BX 316          // LT_STRIDE/32
#define CONV_BY 4            // 128/32

typedef __attribute__((ext_vector_type(4))) float f32x4;
typedef __attribute__((ext_vector_type(2))) short short2v;

__device__ __forceinline__ short f2bf(float f) {
    __hip_bfloat16 h = __float2bfloat16(f);
    return *reinterpret_cast<short*>(&h);
}
__device__ __forceinline__ float bf2f(unsigned short s) {
    unsigned u = ((unsigned)s) << 16;
    return __uint_as_float(u);
}

// async global->LDS 16B (LDS dest = wave-uniform base + lane*16)
__device__ __forceinline__ void gl_lds16(const void* src, void* dst) {
    __builtin_amdgcn_global_load_lds(
        (const __attribute__((address_space(1))) void*)src,
        (__attribute__((address_space(3))) void*)dst, 16, 0, 0);
}

// ---------------------------------------------------------------------------
// prep: seg bounds (blocks 0..2749) + atomic compaction (blocks 2750..)
// ---------------------------------------------------------------------------
__global__ void prep(const int* __restrict__ x, const int* __restrict__ seg_ids,
                     int* __restrict__ flags, int* __restrict__ slotmap,
                     int* __restrict__ rowlist, int* __restrict__ U,
                     int* __restrict__ bounds) {
    int b = blockIdx.x;
    int t = threadIdx.x;
    if (b < BOUND_BLOCKS) {
        int i = b * 256 + t;
        int cur = seg_ids[i];
        int prev = (i == 0) ? -1 : seg_ids[i - 1];
        for (int v = prev + 1; v <= cur; ++v) bounds[v] = i;
        if (i == TOTAL_NGRAMS - 1)
            for (int v = cur + 1; v <= V_WORDS; ++v) bounds[v] = TOTAL_NGRAMS;
    } else {
        int i = (b - BOUND_BLOCKS) * 256 + t;
        if (i < NTOK) {
            int id = x[i];
            if (id >= NSPEC) {
                int v = id - NSPEC;
                if (atomicExch(&flags[v], 1) == 0) {
                    int s = atomicAdd(U, 1);
                    rowlist[s] = v;
                    slotmap[v] = s;
                }
            }
        }
    }
}

// ---------------------------------------------------------------------------
// seg_conv: blocks 0..2047 = EmbeddingBag+tanh (bf16 + fp8 out);
//           blocks 2048..  = latent fp8 convert + fp8 transpose
// ---------------------------------------------------------------------------
__global__ __launch_bounds__(256)
void seg_conv(const int* __restrict__ ngram_ids, const int* __restrict__ bounds,
              const float* __restrict__ W, const int* __restrict__ rowlist,
              const int* __restrict__ Uptr, short* __restrict__ langc,
              unsigned char* __restrict__ langq,
              const float* __restrict__ latent,
              unsigned char* __restrict__ latf8, unsigned char* __restrict__ latT8) {
    __shared__ float tile[32][36];
    int t = threadIdx.x;
    if (blockIdx.x < SEG_BLOCKS) {
        int slot = blockIdx.x * 4 + (t >> 6);
        if (slot >= *Uptr) return;
        int v = rowlist[slot];
        int l = t & 63;
        int start = bounds[v], end = bounds[v + 1];
        float ax = 0.f, ay = 0.f;
        for (int j = start; j < end; ++j) {
            int id = ngram_ids[j];
            float2 row = *reinterpret_cast<const float2*>(W + (size_t)id * DIM + l * 2);
            ax += row.x; ay += row.y;
        }
        float tx = tanhf(ax), ty = tanhf(ay);
        short2v o; o.x = f2bf(tx); o.y = f2bf(ty);
        *reinterpret_cast<short2v*>(langc + (size_t)slot * DIM + l * 2) = o;
        int pk = __builtin_amdgcn_cvt_pk_fp8_f32(tx, ty, 0, false);
        *reinterpret_cast<unsigned short*>(langq + (size_t)slot * DIM + l * 2) =
            (unsigned short)(pk & 0xFFFF);
    } else {
        int bx = blockIdx.x - SEG_BLOCKS;
        int n0 = (bx % CONV_BX) * 32;
        int d0 = (bx / CONV_BX) * 32;
        int nl = t >> 3, dq = t & 7;
        int n = n0 + nl, d = d0 + dq * 4;
        float4 v = {0.f, 0.f, 0.f, 0.f};
        if (n < LATENT) v = *reinterpret_cast<const float4*>(latent + (size_t)n * DIM + d);
        *reinterpret_cast<float4*>(&tile[nl][dq * 4]) = v;
        if (n < LATENT) {
            int pk = __builtin_amdgcn_cvt_pk_fp8_f32(v.x, v.y, 0, false);
            pk = __builtin_amdgcn_cvt_pk_fp8_f32(v.z, v.w, pk, true);
            *reinterpret_cast<unsigned*>(latf8 + (size_t)n * DIM + d) = (unsigned)pk;
        }
        __syncthreads();
#pragma unroll
        for (int u = 0; u < 2; ++u) {
            int it = t + u * 256;
            int dl = it >> 4, np = it & 15;
            float v0 = tile[np * 2][dl], v1 = tile[np * 2 + 1][dl];
            int pk = __builtin_amdgcn_cvt_pk_fp8_f32(v0, v1, 0, false);
            *reinterpret_cast<unsigned short*>(
                latT8 + (size_t)(d0 + dl) * LT_STRIDE + n0 + np * 2) =
                (unsigned short)(pk & 0xFFFF);
        }
    }
}

// ---------------------------------------------------------------------------
// Flash (fp8, 64 q/wave, 1-wave blocks, NO barriers): self-paced pipeline.
// Swapped QK^T -> P lane-local -> cvt_pk_fp8 + permlane{32,16}_swap (no P LDS).
// K/V fp8 LDS tiles (32KB dbuf), global_load_lds, counted vmcnt(16).
// K/V B-frags shared across 4 q-tiles -> LDS read bytes/FLOP halved vs 32q.
// ---------------------------------------------------------------------------
__global__ __launch_bounds__(64, 2)
void flash_latent(const unsigned char* __restrict__ langq,  // fp8 [MAXU][128]
                  const unsigned char* __restrict__ latf8,  // fp8 [LATENT][128]
                  const unsigned char* __restrict__ latT8,  // fp8 [128][LT_STRIDE]
                  const int* __restrict__ Uptr,
                  float* __restrict__ Onum,    // [MAXU][128] f32 (zeroed)
                  float* __restrict__ Dsum) {  // [MAXU] f32 (zeroed)
    const int U = *Uptr;
    const int chunk = blockIdx.x >> 3;   // 0..127
    const int ks = blockIdx.x & 7;       // K-split (aligns with XCD)
    if (chunk * BQBLK >= U) return;

    __shared__ __align__(16) unsigned char Kl[2][BK * DIM];   // 2 x 8KB
    __shared__ __align__(16) unsigned char Vl[2][DIM * BK];   // 2 x 8KB

    const int l = threadIdx.x & 63, l16 = l & 15, g = l >> 4;
    const int g1 = g >> 1, g0 = g & 1;
    const int rowbase = chunk * BQBLK;

    // Q fp8 frags: lane holds Q[qt, row l16][c*32 + g*8 + 0..7]
    long qf[4][4];
#pragma unroll
    for (int qt = 0; qt < 4; ++qt)
#pragma unroll
        for (int c = 0; c < 4; ++c)
            qf[qt][c] = *reinterpret_cast<const long*>(
                langq + (size_t)(rowbase + qt * 16 + l16) * DIM + c * 32 + g * 8);

    f32x4 o[4][8];
#pragma unroll
    for (int qt = 0; qt < 4; ++qt)
#pragma unroll
        for (int s = 0; s < 8; ++s) o[qt][s] = (f32x4){0.f, 0.f, 0.f, 0.f};
    float lsum[4] = {0.f, 0.f, 0.f, 0.f};

    const int kstart = ks * KCH;
    const int kend = (kstart + KCH < LATENT) ? (kstart + KCH) : LATENT;
    const int niter = (kend - kstart + BK - 1) / BK;

    // staging: 512 x 16B chunks each for K and V; 64 lanes -> 8+8 gl_lds/iter
#define STAGE(KT, BUF)                                                              \
    do {                                                                            \
        const int k0s = kstart + (KT) * BK;                                         \
        _Pragma("unroll")                                                           \
        for (int i = 0; i < 8; ++i) {                                               \
            int c = i * 64 + l;                                                     \
            int rr = c >> 3, s16 = c & 7;                                           \
            int gk = k0s + rr; if (gk > LATENT - 1) gk = LATENT - 1;                \
            gl_lds16(latf8 + (size_t)gk * DIM + ((s16 ^ (rr & 7)) * 16),            \
                     &Kl[BUF][i * 1024]);                                           \
        }                                                                           \
        _Pragma("unroll")                                                           \
        for (int i = 0; i < 8; ++i) {                                               \
            int c = i * 64 + l;                                                     \
            int dd = c >> 2, s16 = c & 3;                                           \
            gl_lds16(latT8 + (size_t)dd * LT_STRIDE + k0s + ((s16 ^ (dd & 3)) * 16),\
                     &Vl[BUF][i * 1024]);                                           \
        }                                                                           \
    } while (0)

    STAGE(0, 0);
    int cur = 0;

    for (int kt = 0; kt < niter; ++kt) {
        if (kt + 1 < niter) {
            STAGE(kt + 1, cur ^ 1);
            asm volatile("s_waitcnt vmcnt(16)" ::: "memory");  // tile kt landed
        } else {
            asm volatile("s_waitcnt vmcnt(0)" ::: "memory");
        }
        __builtin_amdgcn_sched_barrier(0);

        const int k0 = kstart + kt * BK;
        const int rem = kend - k0;

        // QK + exp + pack per 16-k subtile (s[] transient)
        int pw[4][4];   // packed exp(S) fp8 words [qt][t4]
#pragma unroll
        for (int t4 = 0; t4 < 4; ++t4) {
            f32x4 s[4];
#pragma unroll
            for (int qt = 0; qt < 4; ++qt) s[qt] = (f32x4){0.f, 0.f, 0.f, 0.f};
            __builtin_amdgcn_s_setprio(1);
#pragma unroll
            for (int c = 0; c < 4; ++c) {
                long af = *reinterpret_cast<const long*>(
                    &Kl[cur][(t4 * 16 + l16) * 128 + (((c * 2 + g1) ^ (l16 & 7)) * 16) + g0 * 8]);
#pragma unroll
                for (int qt = 0; qt < 4; ++qt)
                    s[qt] = __builtin_amdgcn_mfma_f32_16x16x32_fp8_fp8(af, qf[qt][c], s[qt], 0, 0, 0);
            }
            __builtin_amdgcn_s_setprio(0);
            if (rem >= BK) {
#pragma unroll
                for (int qt = 0; qt < 4; ++qt) {
                    float p0 = __expf(s[qt][0]), p1 = __expf(s[qt][1]);
                    float p2 = __expf(s[qt][2]), p3 = __expf(s[qt][3]);
                    lsum[qt] += p0 + p1 + p2 + p3;
                    int qq = __builtin_amdgcn_cvt_pk_fp8_f32(p0, p1, 0, false);
                    pw[qt][t4] = __builtin_amdgcn_cvt_pk_fp8_f32(p2, p3, qq, true);
                }
            } else {
#pragma unroll
                for (int qt = 0; qt < 4; ++qt) {
                    float p[4];
#pragma unroll
                    for (int j = 0; j < 4; ++j) {
                        int kk = t4 * 16 + g * 4 + j;
                        float e = __expf(s[qt][j]);
                        p[j] = (kk < rem) ? e : 0.f;
                        lsum[qt] += p[j];
                    }
                    int qq = __builtin_amdgcn_cvt_pk_fp8_f32(p[0], p[1], 0, false);
                    pw[qt][t4] = __builtin_amdgcn_cvt_pk_fp8_f32(p[2], p[3], qq, true);
                }
            }
        }

        // permlane assembly of PV A-frags
        long pa[4][2];
#pragma unroll
        for (int qt = 0; qt < 4; ++qt) {
            int x0 = pw[qt][0], y0 = pw[qt][1];
            asm volatile("v_permlane32_swap_b32 %0, %1" : "+v"(x0), "+v"(y0));
            asm volatile("v_permlane16_swap_b32 %0, %1" : "+v"(x0), "+v"(y0));
            pa[qt][0] = (long)(((unsigned long)(unsigned)y0 << 32) | (unsigned)x0);
            int x1 = pw[qt][2], y1 = pw[qt][3];
            asm volatile("v_permlane32_swap_b32 %0, %1" : "+v"(x1), "+v"(y1));
            asm volatile("v_permlane16_swap_b32 %0, %1" : "+v"(x1), "+v"(y1));
            pa[qt][1] = (long)(((unsigned long)(unsigned)y1 << 32) | (unsigned)x1);
        }

        // O += P * V  (V B-frags shared across 4 q-tiles)
        __builtin_amdgcn_s_setprio(1);
#pragma unroll
        for (int sub = 0; sub < 8; ++sub) {
#pragma unroll
            for (int kh = 0; kh < 2; ++kh) {
                long bf = *reinterpret_cast<const long*>(
                    &Vl[cur][(sub * 16 + l16) * 64 + ((((kh * 2) + g1) ^ (l16 & 3)) * 16) + g0 * 8]);
#pragma unroll
                for (int qt = 0; qt < 4; ++qt)
                    o[qt][sub] = __builtin_amdgcn_mfma_f32_16x16x32_fp8_fp8(pa[qt][kh], bf, o[qt][sub], 0, 0, 0);
            }
        }
        __builtin_amdgcn_s_setprio(0);
        cur ^= 1;
    }

    // Dsum: reduce across g-groups (lane q-col = l16 per qt)
#pragma unroll
    for (int qt = 0; qt < 4; ++qt) {
        float v = lsum[qt];
        v += __shfl_xor(v, 16, 64);
        v += __shfl_xor(v, 32, 64);
        if (l < 16) atomicAdd(&Dsum[rowbase + qt * 16 + l16], v);
    }
    // Onum: f32 atomics, 16-lane-contiguous (64B sectors) per instruction
#pragma unroll
    for (int sub = 0; sub < 8; ++sub)
#pragma unroll
        for (int qt = 0; qt < 4; ++qt)
#pragma unroll
            for (int j = 0; j < 4; ++j) {
                int row = rowbase + qt * 16 + g * 4 + j;
                atomicAdd(&Onum[(size_t)row * DIM + sub * 16 + l16], o[qt][sub][j]);
            }
}

// ---------------------------------------------------------------------------
// Final gather: 2 tokens per 256-thr block
// ---------------------------------------------------------------------------
__global__ void gather_out(const int* __restrict__ x,
                           const short* __restrict__ langc,
                           const int* __restrict__ slotmap,
                           const float* __restrict__ Onum,
                           const float* __restrict__ Dsum,
                           const float* __restrict__ special,
                           float* __restrict__ out) {
    int i = blockIdx.x * 2 + (threadIdx.x >> 7);
    int t = threadIdx.x & 127;
    int id = x[i];
    float v;
    if (id < NSPEC) {
        v = special[(size_t)id * DIM + t];
    } else {
        int s = slotmap[id - NSPEC];
        v = bf2f((unsigned short)langc[(size_t)s * DIM + t]) +
            Onum[(size_t)s * DIM + t] / Dsum[s];
    }
    out[(size_t)i * DIM + t] = v;
}

// ---------------------------------------------------------------------------
extern "C" void kernel_launch(void* const* d_in, const int* in_sizes, int n_in,
                              void* d_out, int out_size, void* d_ws, size_t ws_size,
                              hipStream_t stream) {
    const int*   x        = (const int*)d_in[0];
    const int*   ngram_id = (const int*)d_in[1];
    const int*   seg_id   = (const int*)d_in[2];
    const float* W        = (const float*)d_in[3];   // [32001,128]
    const float* latent   = (const float*)d_in[4];   // [10000,128]
    const float* special  = (const float*)d_in[5];   // [4,128]
    float* out = (float*)d_out;

    // workspace (~10.4 MB); [Onum|Dsum|flags|Uptr] contiguous -> one memset
    char* ws = (char*)d_ws;
    float* Onum    = (float*)(ws + 0);                       // 4,194,304
    float* Dsum    = (float*)(ws + 4194304);                 //    32,768
    int*   flags   = (int*)(ws + 4227072);                   //   131,072
    int*   Uptr    = (int*)(ws + 4358144);                   //       256
    int*   slotmap = (int*)(ws + 4358400);                   //   128,256
    int*   rowlist = (int*)(ws + 4486656);                   //    32,768
    int*   bounds  = (int*)(ws + 4519424);                   //   128,512
    short* langc   = (short*)(ws + 4647936);                 // 2,097,152
    unsigned char* langq = (unsigned char*)(ws + 6745088);   // 1,048,576
    unsigned char* latf8 = (unsigned char*)(ws + 7793664);   // 1,280,000
    unsigned char* latT8 = (unsigned char*)(ws + 9073664);   // 1,294,336 -> 10,368,000

    hipMemsetAsync(ws, 0, 4358400, stream);  // Onum + Dsum + flags + Uptr

    prep<<<BOUND_BLOCKS + NTOK / 256, 256, 0, stream>>>(
        x, seg_id, flags, slotmap, rowlist, Uptr, bounds);
    seg_conv<<<SEG_BLOCKS + CONV_BX * CONV_BY, 256, 0, stream>>>(
        ngram_id, bounds, W, rowlist, Uptr, langc, langq, latent, latf8, latT8);
    flash_latent<<<(MAXU / BQBLK) * KSPLIT, 64, 0, stream>>>(
        langq, latf8, latT8, Uptr, Onum, Dsum);
    gather_out<<<NTOK / 2, 256, 0, stream>>>(x, langc, slotmap, Onum, Dsum, special, out);
}

// Round 9
// 120.065 us; speedup vs baseline: 1.0889x; 1.0889x over previous
//
#include <hip/hip_runtime.h>
#include <hip/hip_bf16.h>

// Problem constants
#define V_WORDS 32000
#define NSPEC 4
#define DIM 128
#define LATENT 10000
#define LT_STRIDE 10112      // padded fp8 V^T row length (bytes)
#define TOTAL_NGRAMS 704000
#define NTOK 8192
#define MAXU 8192
#define KSPLIT 16
#define KCH 640              // k-range per split (last: 10000-15*640=400)
#define BK 64
#define BQBLK 128            // q rows per block (4 waves x 32)
#define SEG_BLOCKS 2048      // MAXU/4
#define BOUND_BLOCKS 2750    // 704000/256
#define CONV_BX 316          // LT_STRIDE/32
#define CONV_BY 4            // 128/32

typedef __attribute__((ext_vector_type(4))) float f32x4;
typedef __attribute__((ext_vector_type(2))) short short2v;

__device__ __forceinline__ short f2bf(float f) {
    __hip_bfloat16 h = __float2bfloat16(f);
    return *reinterpret_cast<short*>(&h);
}
__device__ __forceinline__ float bf2f(unsigned short s) {
    unsigned u = ((unsigned)s) << 16;
    return __uint_as_float(u);
}

// async global->LDS 16B (LDS dest = wave-uniform base + lane*16)
__device__ __forceinline__ void gl_lds16(const void* src, void* dst) {
    __builtin_amdgcn_global_load_lds(
        (const __attribute__((address_space(1))) void*)src,
        (__attribute__((address_space(3))) void*)dst, 16, 0, 0);
}

// ---------------------------------------------------------------------------
// prep: seg bounds (blocks 0..2749) + atomic compaction (blocks 2750..)
// ---------------------------------------------------------------------------
__global__ void prep(const int* __restrict__ x, const int* __restrict__ seg_ids,
                     int* __restrict__ flags, int* __restrict__ slotmap,
                     int* __restrict__ rowlist, int* __restrict__ U,
                     int* __restrict__ bounds) {
    int b = blockIdx.x;
    int t = threadIdx.x;
    if (b < BOUND_BLOCKS) {
        int i = b * 256 + t;
        int cur = seg_ids[i];
        int prev = (i == 0) ? -1 : seg_ids[i - 1];
        for (int v = prev + 1; v <= cur; ++v) bounds[v] = i;
        if (i == TOTAL_NGRAMS - 1)
            for (int v = cur + 1; v <= V_WORDS; ++v) bounds[v] = TOTAL_NGRAMS;
    } else {
        int i = (b - BOUND_BLOCKS) * 256 + t;
        if (i < NTOK) {
            int id = x[i];
            if (id >= NSPEC) {
                int v = id - NSPEC;
                if (atomicExch(&flags[v], 1) == 0) {
                    int s = atomicAdd(U, 1);
                    rowlist[s] = v;
                    slotmap[v] = s;
                }
            }
        }
    }
}

// ---------------------------------------------------------------------------
// seg_conv: blocks 0..2047 = EmbeddingBag+tanh (bf16 + fp8 out);
//           blocks 2048..  = latent fp8 convert + fp8 transpose
// ---------------------------------------------------------------------------
__global__ __launch_bounds__(256)
void seg_conv(const int* __restrict__ ngram_ids, const int* __restrict__ bounds,
              const float* __restrict__ W, const int* __restrict__ rowlist,
              const int* __restrict__ Uptr, short* __restrict__ langc,
              unsigned char* __restrict__ langq,
              const float* __restrict__ latent,
              unsigned char* __restrict__ latf8, unsigned char* __restrict__ latT8) {
    __shared__ float tile[32][36];
    int t = threadIdx.x;
    if (blockIdx.x < SEG_BLOCKS) {
        int slot = blockIdx.x * 4 + (t >> 6);
        if (slot >= *Uptr) return;
        int v = rowlist[slot];
        int l = t & 63;
        int start = bounds[v], end = bounds[v + 1];
        float ax = 0.f, ay = 0.f;
        for (int j = start; j < end; ++j) {
            int id = ngram_ids[j];
            float2 row = *reinterpret_cast<const float2*>(W + (size_t)id * DIM + l * 2);
            ax += row.x; ay += row.y;
        }
        float tx = tanhf(ax), ty = tanhf(ay);
        short2v o; o.x = f2bf(tx); o.y = f2bf(ty);
        *reinterpret_cast<short2v*>(langc + (size_t)slot * DIM + l * 2) = o;
        int pk = __builtin_amdgcn_cvt_pk_fp8_f32(tx, ty, 0, false);
        *reinterpret_cast<unsigned short*>(langq + (size_t)slot * DIM + l * 2) =
            (unsigned short)(pk & 0xFFFF);
    } else {
        int bx = blockIdx.x - SEG_BLOCKS;
        int n0 = (bx % CONV_BX) * 32;
        int d0 = (bx / CONV_BX) * 32;
        int nl = t >> 3, dq = t & 7;
        int n = n0 + nl, d = d0 + dq * 4;
        float4 v = {0.f, 0.f, 0.f, 0.f};
        if (n < LATENT) v = *reinterpret_cast<const float4*>(latent + (size_t)n * DIM + d);
        *reinterpret_cast<float4*>(&tile[nl][dq * 4]) = v;
        if (n < LATENT) {
            int pk = __builtin_amdgcn_cvt_pk_fp8_f32(v.x, v.y, 0, false);
            pk = __builtin_amdgcn_cvt_pk_fp8_f32(v.z, v.w, pk, true);
            *reinterpret_cast<unsigned*>(latf8 + (size_t)n * DIM + d) = (unsigned)pk;
        }
        __syncthreads();
#pragma unroll
        for (int u = 0; u < 2; ++u) {
            int it = t + u * 256;
            int dl = it >> 4, np = it & 15;
            float v0 = tile[np * 2][dl], v1 = tile[np * 2 + 1][dl];
            int pk = __builtin_amdgcn_cvt_pk_fp8_f32(v0, v1, 0, false);
            *reinterpret_cast<unsigned short*>(
                latT8 + (size_t)(d0 + dl) * LT_STRIDE + n0 + np * 2) =
                (unsigned short)(pk & 0xFFFF);
        }
    }
}

// ---------------------------------------------------------------------------
// Flash (fp8, 32 q/wave, 4-wave blocks, KSPLIT=16): Onum += sum_k exp(S)V.
// Swapped QK^T -> P lane-local -> cvt_pk_fp8 + permlane{32,16}_swap (no P LDS).
// K/V fp8 LDS tiles, global_load_lds dbuf, counted vmcnt.
// K swizzle includes row bit-3 (^((row>>3)&1)<<2) on BOTH stage-source and
// read (matched involution) -> kills the lane l16 / l16+8 same-bank 4-way
// conflict. 912 busy blocks (~3.6/CU -> ~14 waves/CU) hide latency.
// ---------------------------------------------------------------------------
__global__ __launch_bounds__(256, 2)
void flash_latent(const unsigned char* __restrict__ langq,  // fp8 [MAXU][128]
                  const unsigned char* __restrict__ latf8,  // fp8 [LATENT][128]
                  const unsigned char* __restrict__ latT8,  // fp8 [128][LT_STRIDE]
                  const int* __restrict__ Uptr,
                  float* __restrict__ Onum,    // [MAXU][128] f32 (zeroed)
                  float* __restrict__ Dsum) {  // [MAXU] f32 (zeroed)
    const int U = *Uptr;
    const int chunk = blockIdx.x >> 4;   // 0..63
    const int ks = blockIdx.x & 15;      // K-split
    if (chunk * BQBLK >= U) return;

    __shared__ __align__(16) unsigned char Kl[2][BK * DIM];   // 2 x 8KB
    __shared__ __align__(16) unsigned char Vl[2][DIM * BK];   // 2 x 8KB

    const int tid = threadIdx.x;
    const int w = tid >> 6, l = tid & 63, l16 = l & 15, g = l >> 4;
    const int g1 = g >> 1, g0 = g & 1;
    const int rowbase = chunk * BQBLK + w * 32;

    // Q fp8 frags: lane holds Q[rowset r, row l16][c*32 + g*8 + 0..7]
    long qf[2][4];
#pragma unroll
    for (int r = 0; r < 2; ++r)
#pragma unroll
        for (int c = 0; c < 4; ++c)
            qf[r][c] = *reinterpret_cast<const long*>(
                langq + (size_t)(rowbase + r * 16 + l16) * DIM + c * 32 + g * 8);

    f32x4 o[2][8];
#pragma unroll
    for (int r = 0; r < 2; ++r)
#pragma unroll
        for (int s = 0; s < 8; ++s) o[r][s] = (f32x4){0.f, 0.f, 0.f, 0.f};
    float lsum[2] = {0.f, 0.f};

    const int kstart = ks * KCH;
    const int kend = (kstart + KCH < LATENT) ? (kstart + KCH) : LATENT;
    const int niter = (kend - kstart + BK - 1) / BK;

#define STAGE(KT, BUF)                                                              \
    do {                                                                            \
        const int k0s = kstart + (KT) * BK;                                         \
        _Pragma("unroll")                                                           \
        for (int i = 0; i < 2; ++i) {                                               \
            int c = (w * 2 + i) * 64 + l;                                           \
            int rr = c >> 3, s16 = c & 7;                                           \
            int sw = s16 ^ (rr & 7) ^ (((rr >> 3) & 1) << 2);                       \
            int gk = k0s + rr; if (gk > LATENT - 1) gk = LATENT - 1;                \
            gl_lds16(latf8 + (size_t)gk * DIM + sw * 16,                            \
                     &Kl[BUF][(w * 2 + i) * 1024]);                                 \
        }                                                                           \
        _Pragma("unroll")                                                           \
        for (int i = 0; i < 2; ++i) {                                               \
            int c = (w * 2 + i) * 64 + l;                                           \
            int dd = c >> 2, s16 = c & 3;                                           \
            gl_lds16(latT8 + (size_t)dd * LT_STRIDE + k0s + ((s16 ^ (dd & 3)) * 16),\
                     &Vl[BUF][(w * 2 + i) * 1024]);                                 \
        }                                                                           \
    } while (0)

    STAGE(0, 0);
    int cur = 0;

    for (int kt = 0; kt < niter; ++kt) {
        if (kt + 1 < niter) {
            STAGE(kt + 1, cur ^ 1);
            asm volatile("s_waitcnt vmcnt(4)" ::: "memory");
        } else {
            asm volatile("s_waitcnt vmcnt(0)" ::: "memory");
        }
        __builtin_amdgcn_s_barrier();
        __builtin_amdgcn_sched_barrier(0);

        const int k0 = kstart + kt * BK;
        const int rem = kend - k0;

        // S^T = K * Q^T  (K A-frags shared by both rowsets)
        f32x4 s[2][4];
#pragma unroll
        for (int r = 0; r < 2; ++r)
#pragma unroll
            for (int t = 0; t < 4; ++t) s[r][t] = (f32x4){0.f, 0.f, 0.f, 0.f};
        __builtin_amdgcn_s_setprio(1);
#pragma unroll
        for (int t = 0; t < 4; ++t) {
            int row = t * 16 + l16;
#pragma unroll
            for (int c = 0; c < 4; ++c) {
                int slot = (c * 2 + g1) ^ (row & 7) ^ (((row >> 3) & 1) << 2);
                long af = *reinterpret_cast<const long*>(
                    &Kl[cur][row * 128 + slot * 16 + g0 * 8]);
                s[0][t] = __builtin_amdgcn_mfma_f32_16x16x32_fp8_fp8(af, qf[0][c], s[0][t], 0, 0, 0);
                s[1][t] = __builtin_amdgcn_mfma_f32_16x16x32_fp8_fp8(af, qf[1][c], s[1][t], 0, 0, 0);
            }
        }
        __builtin_amdgcn_s_setprio(0);

        // P = exp(S) lane-local; pack fp8; permlane swaps build PV A-frags
        long pa[2][2];
#pragma unroll
        for (int r = 0; r < 2; ++r) {
            int q[4];
            if (rem >= BK) {
#pragma unroll
                for (int t = 0; t < 4; ++t) {
                    float p0 = __expf(s[r][t][0]), p1 = __expf(s[r][t][1]);
                    float p2 = __expf(s[r][t][2]), p3 = __expf(s[r][t][3]);
                    lsum[r] += p0 + p1 + p2 + p3;
                    int qq = __builtin_amdgcn_cvt_pk_fp8_f32(p0, p1, 0, false);
                    q[t] = __builtin_amdgcn_cvt_pk_fp8_f32(p2, p3, qq, true);
                }
            } else {
#pragma unroll
                for (int t = 0; t < 4; ++t) {
                    float p[4];
#pragma unroll
                    for (int j = 0; j < 4; ++j) {
                        int kk = t * 16 + g * 4 + j;
                        float e = __expf(s[r][t][j]);
                        p[j] = (kk < rem) ? e : 0.f;
                        lsum[r] += p[j];
                    }
                    int qq = __builtin_amdgcn_cvt_pk_fp8_f32(p[0], p[1], 0, false);
                    q[t] = __builtin_amdgcn_cvt_pk_fp8_f32(p[2], p[3], qq, true);
                }
            }
            int x0 = q[0], y0 = q[1];
            asm volatile("v_permlane32_swap_b32 %0, %1" : "+v"(x0), "+v"(y0));
            asm volatile("v_permlane16_swap_b32 %0, %1" : "+v"(x0), "+v"(y0));
            pa[r][0] = (long)(((unsigned long)(unsigned)y0 << 32) | (unsigned)x0);
            int x1 = q[2], y1 = q[3];
            asm volatile("v_permlane32_swap_b32 %0, %1" : "+v"(x1), "+v"(y1));
            asm volatile("v_permlane16_swap_b32 %0, %1" : "+v"(x1), "+v"(y1));
            pa[r][1] = (long)(((unsigned long)(unsigned)y1 << 32) | (unsigned)x1);
        }

        // O += P * V
        __builtin_amdgcn_s_setprio(1);
#pragma unroll
        for (int sub = 0; sub < 8; ++sub) {
#pragma unroll
            for (int kh = 0; kh < 2; ++kh) {
                long bf = *reinterpret_cast<const long*>(
                    &Vl[cur][(sub * 16 + l16) * 64 + ((((kh * 2) + g1) ^ (l16 & 3)) * 16) + g0 * 8]);
                o[0][sub] = __builtin_amdgcn_mfma_f32_16x16x32_fp8_fp8(pa[0][kh], bf, o[0][sub], 0, 0, 0);
                o[1][sub] = __builtin_amdgcn_mfma_f32_16x16x32_fp8_fp8(pa[1][kh], bf, o[1][sub], 0, 0, 0);
            }
        }
        __builtin_amdgcn_s_setprio(0);

        __builtin_amdgcn_sched_barrier(0);
        __builtin_amdgcn_s_barrier();
        cur ^= 1;
    }

    // Dsum: reduce across g-groups (lane q-col = l16)
#pragma unroll
    for (int r = 0; r < 2; ++r) {
        float v = lsum[r];
        v += __shfl_xor(v, 16, 64);
        v += __shfl_xor(v, 32, 64);
        if (l < 16) atomicAdd(&Dsum[rowbase + r * 16 + l16], v);
    }
    // Onum: f32 atomics, 16-lane-contiguous (64B sectors) per instruction
#pragma unroll
    for (int sub = 0; sub < 8; ++sub)
#pragma unroll
        for (int r = 0; r < 2; ++r)
#pragma unroll
            for (int j = 0; j < 4; ++j) {
                int row = rowbase + r * 16 + g * 4 + j;
                atomicAdd(&Onum[(size_t)row * DIM + sub * 16 + l16], o[r][sub][j]);
            }
}

// ---------------------------------------------------------------------------
// Final gather: 2 tokens per 256-thr block
// ---------------------------------------------------------------------------
__global__ void gather_out(const int* __restrict__ x,
                           const short* __restrict__ langc,
                           const int* __restrict__ slotmap,
                           const float* __restrict__ Onum,
                           const float* __restrict__ Dsum,
                           const float* __restrict__ special,
                           float* __restrict__ out) {
    int i = blockIdx.x * 2 + (threadIdx.x >> 7);
    int t = threadIdx.x & 127;
    int id = x[i];
    float v;
    if (id < NSPEC) {
        v = special[(size_t)id * DIM + t];
    } else {
        int s = slotmap[id - NSPEC];
        v = bf2f((unsigned short)langc[(size_t)s * DIM + t]) +
            Onum[(size_t)s * DIM + t] / Dsum[s];
    }
    out[(size_t)i * DIM + t] = v;
}

// ---------------------------------------------------------------------------
extern "C" void kernel_launch(void* const* d_in, const int* in_sizes, int n_in,
                              void* d_out, int out_size, void* d_ws, size_t ws_size,
                              hipStream_t stream) {
    const int*   x        = (const int*)d_in[0];
    const int*   ngram_id = (const int*)d_in[1];
    const int*   seg_id   = (const int*)d_in[2];
    const float* W        = (const float*)d_in[3];   // [32001,128]
    const float* latent   = (const float*)d_in[4];   // [10000,128]
    const float* special  = (const float*)d_in[5];   // [4,128]
    float* out = (float*)d_out;

    // workspace (~10.4 MB); [Onum|Dsum|flags|Uptr] contiguous -> one memset
    char* ws = (char*)d_ws;
    float* Onum    = (float*)(ws + 0);                       // 4,194,304
    float* Dsum    = (float*)(ws + 4194304);                 //    32,768
    int*   flags   = (int*)(ws + 4227072);                   //   131,072
    int*   Uptr    = (int*)(ws + 4358144);                   //       256
    int*   slotmap = (int*)(ws + 4358400);                   //   128,256
    int*   rowlist = (int*)(ws + 4486656);                   //    32,768
    int*   bounds  = (int*)(ws + 4519424);                   //   128,512
    short* langc   = (short*)(ws + 4647936);                 // 2,097,152
    unsigned char* langq = (unsigned char*)(ws + 6745088);   // 1,048,576
    unsigned char* latf8 = (unsigned char*)(ws + 7793664);   // 1,280,000
    unsigned char* latT8 = (unsigned char*)(ws + 9073664);   // 1,294,336 -> 10,368,000

    hipMemsetAsync(ws, 0, 4358400, stream);  // Onum + Dsum + flags + Uptr

    prep<<<BOUND_BLOCKS + NTOK / 256, 256, 0, stream>>>(
        x, seg_id, flags, slotmap, rowlist, Uptr, bounds);
    seg_conv<<<SEG_BLOCKS + CONV_BX * CONV_BY, 256, 0, stream>>>(
        ngram_id, bounds, W, rowlist, Uptr, langc, langq, latent, latf8, latT8);
    flash_latent<<<(MAXU / BQBLK) * KSPLIT, 256, 0, stream>>>(
        langq, latf8, latT8, Uptr, Onum, Dsum);
    gather_out<<<NTOK / 2, 256, 0, stream>>>(x, langc, slotmap, Onum, Dsum, special, out);
}

// Round 10
// 117.625 us; speedup vs baseline: 1.1115x; 1.0207x over previous
//
#include <hip/hip_runtime.h>
#include <hip/hip_bf16.h>

// Problem constants
#define V_WORDS 32000
#define NSPEC 4
#define DIM 128
#define LATENT 10000
#define LT_STRIDE 10112      // padded fp8 V^T row length (bytes)
#define TOTAL_NGRAMS 704000
#define NTOK 8192
#define MAXU 8192
#define KSPLIT 16
#define KCH 640              // k-range per split (last: 10000-15*640=400)
#define BK 64
#define BQBLK 128            // q rows per block (4 waves x 32)
#define NCHUNK 64            // MAXU/BQBLK
#define SEG_BLOCKS 2048      // MAXU/4
#define BOUND_BLOCKS 2750    // 704000/256
#define CONV_BX 316          // LT_STRIDE/32
#define CONV_BY 4            // 128/32

typedef __attribute__((ext_vector_type(4))) float f32x4;
typedef __attribute__((ext_vector_type(2))) short short2v;

__device__ __forceinline__ short f2bf(float f) {
    __hip_bfloat16 h = __float2bfloat16(f);
    return *reinterpret_cast<short*>(&h);
}
__device__ __forceinline__ float bf2f(unsigned short s) {
    unsigned u = ((unsigned)s) << 16;
    return __uint_as_float(u);
}

// async global->LDS 16B (LDS dest = wave-uniform base + lane*16)
__device__ __forceinline__ void gl_lds16(const void* src, void* dst) {
    __builtin_amdgcn_global_load_lds(
        (const __attribute__((address_space(1))) void*)src,
        (__attribute__((address_space(3))) void*)dst, 16, 0, 0);
}

// ---------------------------------------------------------------------------
// prep: seg bounds (blocks 0..2749) + atomic compaction (blocks 2750..)
// ---------------------------------------------------------------------------
__global__ void prep(const int* __restrict__ x, const int* __restrict__ seg_ids,
                     int* __restrict__ flags, int* __restrict__ slotmap,
                     int* __restrict__ rowlist, int* __restrict__ U,
                     int* __restrict__ bounds) {
    int b = blockIdx.x;
    int t = threadIdx.x;
    if (b < BOUND_BLOCKS) {
        int i = b * 256 + t;
        int cur = seg_ids[i];
        int prev = (i == 0) ? -1 : seg_ids[i - 1];
        for (int v = prev + 1; v <= cur; ++v) bounds[v] = i;
        if (i == TOTAL_NGRAMS - 1)
            for (int v = cur + 1; v <= V_WORDS; ++v) bounds[v] = TOTAL_NGRAMS;
    } else {
        int i = (b - BOUND_BLOCKS) * 256 + t;
        if (i < NTOK) {
            int id = x[i];
            if (id >= NSPEC) {
                int v = id - NSPEC;
                if (atomicExch(&flags[v], 1) == 0) {
                    int s = atomicAdd(U, 1);
                    rowlist[s] = v;
                    slotmap[v] = s;
                }
            }
        }
    }
}

// ---------------------------------------------------------------------------
// seg_conv: blocks 0..2047 = EmbeddingBag+tanh (bf16 + fp8 out);
//           blocks 2048..  = latent fp8 convert + fp8 transpose
// ---------------------------------------------------------------------------
__global__ __launch_bounds__(256)
void seg_conv(const int* __restrict__ ngram_ids, const int* __restrict__ bounds,
              const float* __restrict__ W, const int* __restrict__ rowlist,
              const int* __restrict__ Uptr, short* __restrict__ langc,
              unsigned char* __restrict__ langq,
              const float* __restrict__ latent,
              unsigned char* __restrict__ latf8, unsigned char* __restrict__ latT8) {
    __shared__ float tile[32][36];
    int t = threadIdx.x;
    if (blockIdx.x < SEG_BLOCKS) {
        int slot = blockIdx.x * 4 + (t >> 6);
        if (slot >= *Uptr) return;
        int v = rowlist[slot];
        int l = t & 63;
        int start = bounds[v], end = bounds[v + 1];
        float ax = 0.f, ay = 0.f;
        for (int j = start; j < end; ++j) {
            int id = ngram_ids[j];
            float2 row = *reinterpret_cast<const float2*>(W + (size_t)id * DIM + l * 2);
            ax += row.x; ay += row.y;
        }
        float tx = tanhf(ax), ty = tanhf(ay);
        short2v o; o.x = f2bf(tx); o.y = f2bf(ty);
        *reinterpret_cast<short2v*>(langc + (size_t)slot * DIM + l * 2) = o;
        int pk = __builtin_amdgcn_cvt_pk_fp8_f32(tx, ty, 0, false);
        *reinterpret_cast<unsigned short*>(langq + (size_t)slot * DIM + l * 2) =
            (unsigned short)(pk & 0xFFFF);
    } else {
        int bx = blockIdx.x - SEG_BLOCKS;
        int n0 = (bx % CONV_BX) * 32;
        int d0 = (bx / CONV_BX) * 32;
        int nl = t >> 3, dq = t & 7;
        int n = n0 + nl, d = d0 + dq * 4;
        float4 v = {0.f, 0.f, 0.f, 0.f};
        if (n < LATENT) v = *reinterpret_cast<const float4*>(latent + (size_t)n * DIM + d);
        *reinterpret_cast<float4*>(&tile[nl][dq * 4]) = v;
        if (n < LATENT) {
            int pk = __builtin_amdgcn_cvt_pk_fp8_f32(v.x, v.y, 0, false);
            pk = __builtin_amdgcn_cvt_pk_fp8_f32(v.z, v.w, pk, true);
            *reinterpret_cast<unsigned*>(latf8 + (size_t)n * DIM + d) = (unsigned)pk;
        }
        __syncthreads();
#pragma unroll
        for (int u = 0; u < 2; ++u) {
            int it = t + u * 256;
            int dl = it >> 4, np = it & 15;
            float v0 = tile[np * 2][dl], v1 = tile[np * 2 + 1][dl];
            int pk = __builtin_amdgcn_cvt_pk_fp8_f32(v0, v1, 0, false);
            *reinterpret_cast<unsigned short*>(
                latT8 + (size_t)(d0 + dl) * LT_STRIDE + n0 + np * 2) =
                (unsigned short)(pk & 0xFFFF);
        }
    }
}

// ---------------------------------------------------------------------------
// Flash (fp8, 32 q/wave, 4-wave blocks, KSPLIT=16, chunk-major XCD map):
//   bid = ks*NCHUNK + chunk  ->  XCD = bid%8 = chunk%8, so ALL K-splits of a
//   chunk share one XCD's L2 -> Onum/Dsum atomics RMW in-cache (not HBM).
// Swapped QK^T -> P lane-local -> cvt_pk_fp8 + permlane{32,16}_swap.
// V LDS swizzle fixed: slot ^= (row>>1)&3 (row-stride 64B; old row&3 made
// lanes l16/l16+4/l16+8/l16+12 collide 4-way). Same involution on stage+read.
// ---------------------------------------------------------------------------
__global__ __launch_bounds__(256, 2)
void flash_latent(const unsigned char* __restrict__ langq,  // fp8 [MAXU][128]
                  const unsigned char* __restrict__ latf8,  // fp8 [LATENT][128]
                  const unsigned char* __restrict__ latT8,  // fp8 [128][LT_STRIDE]
                  const int* __restrict__ Uptr,
                  float* __restrict__ Onum,    // [MAXU][128] f32 (zeroed)
                  float* __restrict__ Dsum) {  // [MAXU] f32 (zeroed)
    const int U = *Uptr;
    const int chunk = blockIdx.x & (NCHUNK - 1);   // 0..63  (XCD = chunk%8)
    const int ks = blockIdx.x >> 6;                // 0..15
    if (chunk * BQBLK >= U) return;

    __shared__ __align__(16) unsigned char Kl[2][BK * DIM];   // 2 x 8KB
    __shared__ __align__(16) unsigned char Vl[2][DIM * BK];   // 2 x 8KB

    const int tid = threadIdx.x;
    const int w = tid >> 6, l = tid & 63, l16 = l & 15, g = l >> 4;
    const int g1 = g >> 1, g0 = g & 1;
    const int rowbase = chunk * BQBLK + w * 32;

    // Q fp8 frags: lane holds Q[rowset r, row l16][c*32 + g*8 + 0..7]
    long qf[2][4];
#pragma unroll
    for (int r = 0; r < 2; ++r)
#pragma unroll
        for (int c = 0; c < 4; ++c)
            qf[r][c] = *reinterpret_cast<const long*>(
                langq + (size_t)(rowbase + r * 16 + l16) * DIM + c * 32 + g * 8);

    f32x4 o[2][8];
#pragma unroll
    for (int r = 0; r < 2; ++r)
#pragma unroll
        for (int s = 0; s < 8; ++s) o[r][s] = (f32x4){0.f, 0.f, 0.f, 0.f};
    float lsum[2] = {0.f, 0.f};

    const int kstart = ks * KCH;
    const int kend = (kstart + KCH < LATENT) ? (kstart + KCH) : LATENT;
    const int niter = (kend - kstart + BK - 1) / BK;

#define STAGE(KT, BUF)                                                              \
    do {                                                                            \
        const int k0s = kstart + (KT) * BK;                                         \
        _Pragma("unroll")                                                           \
        for (int i = 0; i < 2; ++i) {                                               \
            int c = (w * 2 + i) * 64 + l;                                           \
            int rr = c >> 3, s16 = c & 7;                                           \
            int sw = s16 ^ (rr & 7) ^ (((rr >> 3) & 1) << 2);                       \
            int gk = k0s + rr; if (gk > LATENT - 1) gk = LATENT - 1;                \
            gl_lds16(latf8 + (size_t)gk * DIM + sw * 16,                            \
                     &Kl[BUF][(w * 2 + i) * 1024]);                                 \
        }                                                                           \
        _Pragma("unroll")                                                           \
        for (int i = 0; i < 2; ++i) {                                               \
            int c = (w * 2 + i) * 64 + l;                                           \
            int dd = c >> 2, s16 = c & 3;                                           \
            int sw = s16 ^ ((dd >> 1) & 3);                                         \
            gl_lds16(latT8 + (size_t)dd * LT_STRIDE + k0s + sw * 16,                \
                     &Vl[BUF][(w * 2 + i) * 1024]);                                 \
        }                                                                           \
    } while (0)

    STAGE(0, 0);
    int cur = 0;

    for (int kt = 0; kt < niter; ++kt) {
        if (kt + 1 < niter) {
            STAGE(kt + 1, cur ^ 1);
            asm volatile("s_waitcnt vmcnt(4)" ::: "memory");
        } else {
            asm volatile("s_waitcnt vmcnt(0)" ::: "memory");
        }
        __builtin_amdgcn_s_barrier();
        __builtin_amdgcn_sched_barrier(0);

        const int k0 = kstart + kt * BK;
        const int rem = kend - k0;

        // S^T = K * Q^T  (K A-frags shared by both rowsets)
        f32x4 s[2][4];
#pragma unroll
        for (int r = 0; r < 2; ++r)
#pragma unroll
            for (int t = 0; t < 4; ++t) s[r][t] = (f32x4){0.f, 0.f, 0.f, 0.f};
        __builtin_amdgcn_s_setprio(1);
#pragma unroll
        for (int t = 0; t < 4; ++t) {
            int row = t * 16 + l16;
#pragma unroll
            for (int c = 0; c < 4; ++c) {
                int slot = (c * 2 + g1) ^ (row & 7) ^ (((row >> 3) & 1) << 2);
                long af = *reinterpret_cast<const long*>(
                    &Kl[cur][row * 128 + slot * 16 + g0 * 8]);
                s[0][t] = __builtin_amdgcn_mfma_f32_16x16x32_fp8_fp8(af, qf[0][c], s[0][t], 0, 0, 0);
                s[1][t] = __builtin_amdgcn_mfma_f32_16x16x32_fp8_fp8(af, qf[1][c], s[1][t], 0, 0, 0);
            }
        }
        __builtin_amdgcn_s_setprio(0);

        // P = exp(S) lane-local; pack fp8; permlane swaps build PV A-frags
        long pa[2][2];
#pragma unroll
        for (int r = 0; r < 2; ++r) {
            int q[4];
            if (rem >= BK) {
#pragma unroll
                for (int t = 0; t < 4; ++t) {
                    float p0 = __expf(s[r][t][0]), p1 = __expf(s[r][t][1]);
                    float p2 = __expf(s[r][t][2]), p3 = __expf(s[r][t][3]);
                    lsum[r] += p0 + p1 + p2 + p3;
                    int qq = __builtin_amdgcn_cvt_pk_fp8_f32(p0, p1, 0, false);
                    q[t] = __builtin_amdgcn_cvt_pk_fp8_f32(p2, p3, qq, true);
                }
            } else {
#pragma unroll
                for (int t = 0; t < 4; ++t) {
                    float p[4];
#pragma unroll
                    for (int j = 0; j < 4; ++j) {
                        int kk = t * 16 + g * 4 + j;
                        float e = __expf(s[r][t][j]);
                        p[j] = (kk < rem) ? e : 0.f;
                        lsum[r] += p[j];
                    }
                    int qq = __builtin_amdgcn_cvt_pk_fp8_f32(p[0], p[1], 0, false);
                    q[t] = __builtin_amdgcn_cvt_pk_fp8_f32(p[2], p[3], qq, true);
                }
            }
            int x0 = q[0], y0 = q[1];
            asm volatile("v_permlane32_swap_b32 %0, %1" : "+v"(x0), "+v"(y0));
            asm volatile("v_permlane16_swap_b32 %0, %1" : "+v"(x0), "+v"(y0));
            pa[r][0] = (long)(((unsigned long)(unsigned)y0 << 32) | (unsigned)x0);
            int x1 = q[2], y1 = q[3];
            asm volatile("v_permlane32_swap_b32 %0, %1" : "+v"(x1), "+v"(y1));
            asm volatile("v_permlane16_swap_b32 %0, %1" : "+v"(x1), "+v"(y1));
            pa[r][1] = (long)(((unsigned long)(unsigned)y1 << 32) | (unsigned)x1);
        }

        // O += P * V   (V slot swizzle = (row>>1)&3 — conflict-free)
        __builtin_amdgcn_s_setprio(1);
#pragma unroll
        for (int sub = 0; sub < 8; ++sub) {
#pragma unroll
            for (int kh = 0; kh < 2; ++kh) {
                int slot = (kh * 2 + g1) ^ ((l16 >> 1) & 3);
                long bf = *reinterpret_cast<const long*>(
                    &Vl[cur][(sub * 16 + l16) * 64 + slot * 16 + g0 * 8]);
                o[0][sub] = __builtin_amdgcn_mfma_f32_16x16x32_fp8_fp8(pa[0][kh], bf, o[0][sub], 0, 0, 0);
                o[1][sub] = __builtin_amdgcn_mfma_f32_16x16x32_fp8_fp8(pa[1][kh], bf, o[1][sub], 0, 0, 0);
            }
        }
        __builtin_amdgcn_s_setprio(0);

        __builtin_amdgcn_sched_barrier(0);
        __builtin_amdgcn_s_barrier();
        cur ^= 1;
    }

    // Dsum: reduce across g-groups (lane q-col = l16)
#pragma unroll
    for (int r = 0; r < 2; ++r) {
        float v = lsum[r];
        v += __shfl_xor(v, 16, 64);
        v += __shfl_xor(v, 32, 64);
        if (l < 16) atomicAdd(&Dsum[rowbase + r * 16 + l16], v);
    }
    // Onum: f32 atomics, 16-lane-contiguous (64B lines, all ks on same XCD L2)
#pragma unroll
    for (int sub = 0; sub < 8; ++sub)
#pragma unroll
        for (int r = 0; r < 2; ++r)
#pragma unroll
            for (int j = 0; j < 4; ++j) {
                int row = rowbase + r * 16 + g * 4 + j;
                atomicAdd(&Onum[(size_t)row * DIM + sub * 16 + l16], o[r][sub][j]);
            }
}

// ---------------------------------------------------------------------------
// Final gather: 2 tokens per 256-thr block
// ---------------------------------------------------------------------------
__global__ void gather_out(const int* __restrict__ x,
                           const short* __restrict__ langc,
                           const int* __restrict__ slotmap,
                           const float* __restrict__ Onum,
                           const float* __restrict__ Dsum,
                           const float* __restrict__ special,
                           float* __restrict__ out) {
    int i = blockIdx.x * 2 + (threadIdx.x >> 7);
    int t = threadIdx.x & 127;
    int id = x[i];
    float v;
    if (id < NSPEC) {
        v = special[(size_t)id * DIM + t];
    } else {
        int s = slotmap[id - NSPEC];
        v = bf2f((unsigned short)langc[(size_t)s * DIM + t]) +
            Onum[(size_t)s * DIM + t] / Dsum[s];
    }
    out[(size_t)i * DIM + t] = v;
}

// ---------------------------------------------------------------------------
extern "C" void kernel_launch(void* const* d_in, const int* in_sizes, int n_in,
                              void* d_out, int out_size, void* d_ws, size_t ws_size,
                              hipStream_t stream) {
    const int*   x        = (const int*)d_in[0];
    const int*   ngram_id = (const int*)d_in[1];
    const int*   seg_id   = (const int*)d_in[2];
    const float* W        = (const float*)d_in[3];   // [32001,128]
    const float* latent   = (const float*)d_in[4];   // [10000,128]
    const float* special  = (const float*)d_in[5];   // [4,128]
    float* out = (float*)d_out;

    // workspace (~10.4 MB); [Onum|Dsum|flags|Uptr] contiguous -> one memset
    char* ws = (char*)d_ws;
    float* Onum    = (float*)(ws + 0);                       // 4,194,304
    float* Dsum    = (float*)(ws + 4194304);                 //    32,768
    int*   flags   = (int*)(ws + 4227072);                   //   131,072
    int*   Uptr    = (int*)(ws + 4358144);                   //       256
    int*   slotmap = (int*)(ws + 4358400);                   //   128,256
    int*   rowlist = (int*)(ws + 4486656);                   //    32,768
    int*   bounds  = (int*)(ws + 4519424);                   //   128,512
    short* langc   = (short*)(ws + 4647936);                 // 2,097,152
    unsigned char* langq = (unsigned char*)(ws + 6745088);   // 1,048,576
    unsigned char* latf8 = (unsigned char*)(ws + 7793664);   // 1,280,000
    unsigned char* latT8 = (unsigned char*)(ws + 9073664);   // 1,294,336 -> 10,368,000

    hipMemsetAsync(ws, 0, 4358400, stream);  // Onum + Dsum + flags + Uptr

    prep<<<BOUND_BLOCKS + NTOK / 256, 256, 0, stream>>>(
        x, seg_id, flags, slotmap, rowlist, Uptr, bounds);
    seg_conv<<<SEG_BLOCKS + CONV_BX * CONV_BY, 256, 0, stream>>>(
        ngram_id, bounds, W, rowlist, Uptr, langc, langq, latent, latf8, latT8);
    flash_latent<<<NCHUNK * KSPLIT, 256, 0, stream>>>(
        langq, latf8, latT8, Uptr, Onum, Dsum);
    gather_out<<<NTOK / 2, 256, 0, stream>>>(x, langc, slotmap, Onum, Dsum, special, out);
}

// Round 11
// 98.337 us; speedup vs baseline: 1.3295x; 1.1961x over previous
//
#include <hip/hip_runtime.h>
#include <hip/hip_bf16.h>

// Problem constants
#define V_WORDS 32000
#define NSPEC 4
#define DIM 128
#define LATENT 10000
#define LT_STRIDE 10112      // padded fp8 V^T row length (bytes)
#define TOTAL_NGRAMS 704000
#define NTOK 8192
#define MAXU 8192
#define KSPLIT 9
#define KCH 1152             // 8*1152=9216; last split covers 784
#define BK 64
#define BQBLK 128            // q rows per block (4 waves x 32)
#define NCHUNK 64            // MAXU/BQBLK
#define SEG_BLOCKS 2048      // MAXU/4
#define BOUND_BLOCKS 2750    // 704000/256
#define CONV_BX 316          // LT_STRIDE/32
#define CONV_BY 4            // 128/32

typedef __attribute__((ext_vector_type(4))) float f32x4;
typedef __attribute__((ext_vector_type(2))) short short2v;

__device__ __forceinline__ short f2bf(float f) {
    __hip_bfloat16 h = __float2bfloat16(f);
    return *reinterpret_cast<short*>(&h);
}
__device__ __forceinline__ float bf2f(unsigned short s) {
    unsigned u = ((unsigned)s) << 16;
    return __uint_as_float(u);
}
__device__ __forceinline__ unsigned pk_bf16(float lo, float hi) {
    unsigned r;
    asm volatile("v_cvt_pk_bf16_f32 %0, %1, %2" : "=v"(r) : "v"(lo), "v"(hi));
    return r;
}
__device__ __forceinline__ void atom_pk_bf16(unsigned short* addr, unsigned val) {
    asm volatile("global_atomic_pk_add_bf16 %0, %1, off"
                 :: "v"(addr), "v"(val) : "memory");
}

// async global->LDS 16B (LDS dest = wave-uniform base + lane*16)
__device__ __forceinline__ void gl_lds16(const void* src, void* dst) {
    __builtin_amdgcn_global_load_lds(
        (const __attribute__((address_space(1))) void*)src,
        (__attribute__((address_space(3))) void*)dst, 16, 0, 0);
}

// ---------------------------------------------------------------------------
// prep: seg bounds (blocks 0..2749) + atomic compaction (blocks 2750..)
// ---------------------------------------------------------------------------
__global__ void prep(const int* __restrict__ x, const int* __restrict__ seg_ids,
                     int* __restrict__ flags, int* __restrict__ slotmap,
                     int* __restrict__ rowlist, int* __restrict__ U,
                     int* __restrict__ bounds) {
    int b = blockIdx.x;
    int t = threadIdx.x;
    if (b < BOUND_BLOCKS) {
        int i = b * 256 + t;
        int cur = seg_ids[i];
        int prev = (i == 0) ? -1 : seg_ids[i - 1];
        for (int v = prev + 1; v <= cur; ++v) bounds[v] = i;
        if (i == TOTAL_NGRAMS - 1)
            for (int v = cur + 1; v <= V_WORDS; ++v) bounds[v] = TOTAL_NGRAMS;
    } else {
        int i = (b - BOUND_BLOCKS) * 256 + t;
        if (i < NTOK) {
            int id = x[i];
            if (id >= NSPEC) {
                int v = id - NSPEC;
                if (atomicExch(&flags[v], 1) == 0) {
                    int s = atomicAdd(U, 1);
                    rowlist[s] = v;
                    slotmap[v] = s;
                }
            }
        }
    }
}

// ---------------------------------------------------------------------------
// seg_conv: blocks 0..2047 = EmbeddingBag+tanh (bf16 + fp8 out);
//           blocks 2048..  = latent fp8 convert + fp8 transpose
// ---------------------------------------------------------------------------
__global__ __launch_bounds__(256)
void seg_conv(const int* __restrict__ ngram_ids, const int* __restrict__ bounds,
              const float* __restrict__ W, const int* __restrict__ rowlist,
              const int* __restrict__ Uptr, short* __restrict__ langc,
              unsigned char* __restrict__ langq,
              const float* __restrict__ latent,
              unsigned char* __restrict__ latf8, unsigned char* __restrict__ latT8) {
    __shared__ float tile[32][36];
    int t = threadIdx.x;
    if (blockIdx.x < SEG_BLOCKS) {
        int slot = blockIdx.x * 4 + (t >> 6);
        if (slot >= *Uptr) return;
        int v = rowlist[slot];
        int l = t & 63;
        int start = bounds[v], end = bounds[v + 1];
        float ax = 0.f, ay = 0.f;
        for (int j = start; j < end; ++j) {
            int id = ngram_ids[j];
            float2 row = *reinterpret_cast<const float2*>(W + (size_t)id * DIM + l * 2);
            ax += row.x; ay += row.y;
        }
        float tx = tanhf(ax), ty = tanhf(ay);
        short2v o; o.x = f2bf(tx); o.y = f2bf(ty);
        *reinterpret_cast<short2v*>(langc + (size_t)slot * DIM + l * 2) = o;
        int pk = __builtin_amdgcn_cvt_pk_fp8_f32(tx, ty, 0, false);
        *reinterpret_cast<unsigned short*>(langq + (size_t)slot * DIM + l * 2) =
            (unsigned short)(pk & 0xFFFF);
    } else {
        int bx = blockIdx.x - SEG_BLOCKS;
        int n0 = (bx % CONV_BX) * 32;
        int d0 = (bx / CONV_BX) * 32;
        int nl = t >> 3, dq = t & 7;
        int n = n0 + nl, d = d0 + dq * 4;
        float4 v = {0.f, 0.f, 0.f, 0.f};
        if (n < LATENT) v = *reinterpret_cast<const float4*>(latent + (size_t)n * DIM + d);
        *reinterpret_cast<float4*>(&tile[nl][dq * 4]) = v;
        if (n < LATENT) {
            int pk = __builtin_amdgcn_cvt_pk_fp8_f32(v.x, v.y, 0, false);
            pk = __builtin_amdgcn_cvt_pk_fp8_f32(v.z, v.w, pk, true);
            *reinterpret_cast<unsigned*>(latf8 + (size_t)n * DIM + d) = (unsigned)pk;
        }
        __syncthreads();
#pragma unroll
        for (int u = 0; u < 2; ++u) {
            int it = t + u * 256;
            int dl = it >> 4, np = it & 15;
            float v0 = tile[np * 2][dl], v1 = tile[np * 2 + 1][dl];
            int pk = __builtin_amdgcn_cvt_pk_fp8_f32(v0, v1, 0, false);
            *reinterpret_cast<unsigned short*>(
                latT8 + (size_t)(d0 + dl) * LT_STRIDE + n0 + np * 2) =
                (unsigned short)(pk & 0xFFFF);
        }
    }
}

// ---------------------------------------------------------------------------
// Flash (fp8, 32 q/wave, 4-wave blocks, KSPLIT=9 ks-minor):
//   OnumB (bf16) += sum_k exp(S)V via global_atomic_pk_add_bf16 (half the
//   ops+bytes of f32); pairing done in-register with shfl_xor(1): lane l16
//   owns col-pair c0 = u*32 + (l16&14) + 16*(l16&1)  (XOR-friendly bijection,
//   full 64B line segments per row per instruction).
// Swapped QK^T -> P lane-local -> cvt_pk_fp8 + permlane{32,16}_swap.
// V LDS swizzle: slot ^= (row>>1)&3 (conflict-free, fixed in r10).
// ---------------------------------------------------------------------------
__global__ __launch_bounds__(256, 2)
void flash_latent(const unsigned char* __restrict__ langq,  // fp8 [MAXU][128]
                  const unsigned char* __restrict__ latf8,  // fp8 [LATENT][128]
                  const unsigned char* __restrict__ latT8,  // fp8 [128][LT_STRIDE]
                  const int* __restrict__ Uptr,
                  unsigned short* __restrict__ OnumB,  // [MAXU][128] bf16 (zeroed)
                  float* __restrict__ Dsum) {          // [MAXU] f32 (zeroed)
    const int U = *Uptr;
    const int chunk = blockIdx.x / KSPLIT;   // 0..63
    const int ks = blockIdx.x % KSPLIT;      // 0..8 (minor -> L2 reuse of slice)
    if (chunk * BQBLK >= U) return;

    __shared__ __align__(16) unsigned char Kl[2][BK * DIM];   // 2 x 8KB
    __shared__ __align__(16) unsigned char Vl[2][DIM * BK];   // 2 x 8KB

    const int tid = threadIdx.x;
    const int w = tid >> 6, l = tid & 63, l16 = l & 15, g = l >> 4;
    const int g1 = g >> 1, g0 = g & 1;
    const int rowbase = chunk * BQBLK + w * 32;

    // Q fp8 frags: lane holds Q[rowset r, row l16][c*32 + g*8 + 0..7]
    long qf[2][4];
#pragma unroll
    for (int r = 0; r < 2; ++r)
#pragma unroll
        for (int c = 0; c < 4; ++c)
            qf[r][c] = *reinterpret_cast<const long*>(
                langq + (size_t)(rowbase + r * 16 + l16) * DIM + c * 32 + g * 8);

    f32x4 o[2][8];
#pragma unroll
    for (int r = 0; r < 2; ++r)
#pragma unroll
        for (int s = 0; s < 8; ++s) o[r][s] = (f32x4){0.f, 0.f, 0.f, 0.f};
    float lsum[2] = {0.f, 0.f};

    const int kstart = ks * KCH;
    const int kend = (kstart + KCH < LATENT) ? (kstart + KCH) : LATENT;
    const int niter = (kend - kstart + BK - 1) / BK;

#define STAGE(KT, BUF)                                                              \
    do {                                                                            \
        const int k0s = kstart + (KT) * BK;                                         \
        _Pragma("unroll")                                                           \
        for (int i = 0; i < 2; ++i) {                                               \
            int c = (w * 2 + i) * 64 + l;                                           \
            int rr = c >> 3, s16 = c & 7;                                           \
            int sw = s16 ^ (rr & 7) ^ (((rr >> 3) & 1) << 2);                       \
            int gk = k0s + rr; if (gk > LATENT - 1) gk = LATENT - 1;                \
            gl_lds16(latf8 + (size_t)gk * DIM + sw * 16,                            \
                     &Kl[BUF][(w * 2 + i) * 1024]);                                 \
        }                                                                           \
        _Pragma("unroll")                                                           \
        for (int i = 0; i < 2; ++i) {                                               \
            int c = (w * 2 + i) * 64 + l;                                           \
            int dd = c >> 2, s16 = c & 3;                                           \
            int sw = s16 ^ ((dd >> 1) & 3);                                         \
            gl_lds16(latT8 + (size_t)dd * LT_STRIDE + k0s + sw * 16,                \
                     &Vl[BUF][(w * 2 + i) * 1024]);                                 \
        }                                                                           \
    } while (0)

    STAGE(0, 0);
    int cur = 0;

    for (int kt = 0; kt < niter; ++kt) {
        if (kt + 1 < niter) {
            STAGE(kt + 1, cur ^ 1);
            asm volatile("s_waitcnt vmcnt(4)" ::: "memory");
        } else {
            asm volatile("s_waitcnt vmcnt(0)" ::: "memory");
        }
        __builtin_amdgcn_s_barrier();
        __builtin_amdgcn_sched_barrier(0);

        const int k0 = kstart + kt * BK;
        const int rem = kend - k0;

        // S^T = K * Q^T  (K A-frags shared by both rowsets)
        f32x4 s[2][4];
#pragma unroll
        for (int r = 0; r < 2; ++r)
#pragma unroll
            for (int t = 0; t < 4; ++t) s[r][t] = (f32x4){0.f, 0.f, 0.f, 0.f};
        __builtin_amdgcn_s_setprio(1);
#pragma unroll
        for (int t = 0; t < 4; ++t) {
            int row = t * 16 + l16;
#pragma unroll
            for (int c = 0; c < 4; ++c) {
                int slot = (c * 2 + g1) ^ (row & 7) ^ (((row >> 3) & 1) << 2);
                long af = *reinterpret_cast<const long*>(
                    &Kl[cur][row * 128 + slot * 16 + g0 * 8]);
                s[0][t] = __builtin_amdgcn_mfma_f32_16x16x32_fp8_fp8(af, qf[0][c], s[0][t], 0, 0, 0);
                s[1][t] = __builtin_amdgcn_mfma_f32_16x16x32_fp8_fp8(af, qf[1][c], s[1][t], 0, 0, 0);
            }
        }
        __builtin_amdgcn_s_setprio(0);

        // P = exp(S) lane-local; pack fp8; permlane swaps build PV A-frags
        long pa[2][2];
#pragma unroll
        for (int r = 0; r < 2; ++r) {
            int q[4];
            if (rem >= BK) {
#pragma unroll
                for (int t = 0; t < 4; ++t) {
                    float p0 = __expf(s[r][t][0]), p1 = __expf(s[r][t][1]);
                    float p2 = __expf(s[r][t][2]), p3 = __expf(s[r][t][3]);
                    lsum[r] += p0 + p1 + p2 + p3;
                    int qq = __builtin_amdgcn_cvt_pk_fp8_f32(p0, p1, 0, false);
                    q[t] = __builtin_amdgcn_cvt_pk_fp8_f32(p2, p3, qq, true);
                }
            } else {
#pragma unroll
                for (int t = 0; t < 4; ++t) {
                    float p[4];
#pragma unroll
                    for (int j = 0; j < 4; ++j) {
                        int kk = t * 16 + g * 4 + j;
                        float e = __expf(s[r][t][j]);
                        p[j] = (kk < rem) ? e : 0.f;
                        lsum[r] += p[j];
                    }
                    int qq = __builtin_amdgcn_cvt_pk_fp8_f32(p[0], p[1], 0, false);
                    q[t] = __builtin_amdgcn_cvt_pk_fp8_f32(p[2], p[3], qq, true);
                }
            }
            int x0 = q[0], y0 = q[1];
            asm volatile("v_permlane32_swap_b32 %0, %1" : "+v"(x0), "+v"(y0));
            asm volatile("v_permlane16_swap_b32 %0, %1" : "+v"(x0), "+v"(y0));
            pa[r][0] = (long)(((unsigned long)(unsigned)y0 << 32) | (unsigned)x0);
            int x1 = q[2], y1 = q[3];
            asm volatile("v_permlane32_swap_b32 %0, %1" : "+v"(x1), "+v"(y1));
            asm volatile("v_permlane16_swap_b32 %0, %1" : "+v"(x1), "+v"(y1));
            pa[r][1] = (long)(((unsigned long)(unsigned)y1 << 32) | (unsigned)x1);
        }

        // O += P * V   (V slot swizzle = (row>>1)&3 — conflict-free)
        __builtin_amdgcn_s_setprio(1);
#pragma unroll
        for (int sub = 0; sub < 8; ++sub) {
#pragma unroll
            for (int kh = 0; kh < 2; ++kh) {
                int slot = (kh * 2 + g1) ^ ((l16 >> 1) & 3);
                long bf = *reinterpret_cast<const long*>(
                    &Vl[cur][(sub * 16 + l16) * 64 + slot * 16 + g0 * 8]);
                o[0][sub] = __builtin_amdgcn_mfma_f32_16x16x32_fp8_fp8(pa[0][kh], bf, o[0][sub], 0, 0, 0);
                o[1][sub] = __builtin_amdgcn_mfma_f32_16x16x32_fp8_fp8(pa[1][kh], bf, o[1][sub], 0, 0, 0);
            }
        }
        __builtin_amdgcn_s_setprio(0);

        __builtin_amdgcn_sched_barrier(0);
        __builtin_amdgcn_s_barrier();
        cur ^= 1;
    }

    // Dsum: reduce across g-groups (lane q-col = l16)
#pragma unroll
    for (int r = 0; r < 2; ++r) {
        float v = lsum[r];
        v += __shfl_xor(v, 16, 64);
        v += __shfl_xor(v, 32, 64);
        if (l < 16) atomicAdd(&Dsum[rowbase + r * 16 + l16], v);
    }

    // OnumB: packed bf16 atomics. Lane l16 owns col-pair
    //   c0 = u*32 + (l16&14) + 16*(l16&1):
    //   l16 even -> (ve[l16], ve[l16^1]) ; l16 odd -> (vo[l16^1], vo[l16])
    const bool oddl = (l16 & 1) != 0;
#pragma unroll
    for (int r = 0; r < 2; ++r)
#pragma unroll
        for (int u = 0; u < 4; ++u)
#pragma unroll
            for (int j = 0; j < 4; ++j) {
                float ve = o[r][2 * u][j];       // col = u*32 + l16
                float vo = o[r][2 * u + 1][j];   // col = u*32 + 16 + l16
                float e1 = __shfl_xor(ve, 1, 64);
                float o1 = __shfl_xor(vo, 1, 64);
                float lo = oddl ? o1 : ve;
                float hi = oddl ? vo : e1;
                unsigned pkv = pk_bf16(lo, hi);
                int row = rowbase + r * 16 + g * 4 + j;
                int c0 = u * 32 + (l16 & 14) + ((l16 & 1) << 4);
                atom_pk_bf16(OnumB + (size_t)row * DIM + c0, pkv);
            }
}

// ---------------------------------------------------------------------------
// Final gather: 2 tokens per 256-thr block
// ---------------------------------------------------------------------------
__global__ void gather_out(const int* __restrict__ x,
                           const short* __restrict__ langc,
                           const int* __restrict__ slotmap,
                           const unsigned short* __restrict__ OnumB,
                           const float* __restrict__ Dsum,
                           const float* __restrict__ special,
                           float* __restrict__ out) {
    int i = blockIdx.x * 2 + (threadIdx.x >> 7);
    int t = threadIdx.x & 127;
    int id = x[i];
    float v;
    if (id < NSPEC) {
        v = special[(size_t)id * DIM + t];
    } else {
        int s = slotmap[id - NSPEC];
        v = bf2f((unsigned short)langc[(size_t)s * DIM + t]) +
            bf2f(OnumB[(size_t)s * DIM + t]) / Dsum[s];
    }
    out[(size_t)i * DIM + t] = v;
}

// ---------------------------------------------------------------------------
extern "C" void kernel_launch(void* const* d_in, const int* in_sizes, int n_in,
                              void* d_out, int out_size, void* d_ws, size_t ws_size,
                              hipStream_t stream) {
    const int*   x        = (const int*)d_in[0];
    const int*   ngram_id = (const int*)d_in[1];
    const int*   seg_id   = (const int*)d_in[2];
    const float* W        = (const float*)d_in[3];   // [32001,128]
    const float* latent   = (const float*)d_in[4];   // [10000,128]
    const float* special  = (const float*)d_in[5];   // [4,128]
    float* out = (float*)d_out;

    // workspace (~8.3 MB); [OnumB|Dsum|flags|Uptr] contiguous -> one memset
    char* ws = (char*)d_ws;
    unsigned short* OnumB = (unsigned short*)(ws + 0);       // 2,097,152
    float* Dsum    = (float*)(ws + 2097152);                 //    32,768
    int*   flags   = (int*)(ws + 2129920);                   //   131,072
    int*   Uptr    = (int*)(ws + 2260992);                   //       256
    int*   slotmap = (int*)(ws + 2261248);                   //   128,256
    int*   rowlist = (int*)(ws + 2389504);                   //    32,768
    int*   bounds  = (int*)(ws + 2422272);                   //   128,512
    short* langc   = (short*)(ws + 2550784);                 // 2,097,152
    unsigned char* langq = (unsigned char*)(ws + 4647936);   // 1,048,576
    unsigned char* latf8 = (unsigned char*)(ws + 5696512);   // 1,280,000
    unsigned char* latT8 = (unsigned char*)(ws + 6976512);   // 1,294,336 -> 8,270,848

    hipMemsetAsync(ws, 0, 2261248, stream);  // OnumB + Dsum + flags + Uptr

    prep<<<BOUND_BLOCKS + NTOK / 256, 256, 0, stream>>>(
        x, seg_id, flags, slotmap, rowlist, Uptr, bounds);
    seg_conv<<<SEG_BLOCKS + CONV_BX * CONV_BY, 256, 0, stream>>>(
        ngram_id, bounds, W, rowlist, Uptr, langc, langq, latent, latf8, latT8);
    flash_latent<<<NCHUNK * KSPLIT, 256, 0, stream>>>(
        langq, latf8, latT8, Uptr, OnumB, Dsum);
    gather_out<<<NTOK / 2, 256, 0, stream>>>(x, langc, slotmap, OnumB, Dsum, special, out);
}